// Round 5
// baseline (20702.534 us; speedup 1.0000x reference)
//
#include <hip/hip_runtime.h>
#include <hip/hip_bf16.h>
#include <math.h>

#define T_STEPS 4096
#define IN_DIM  512
#define HID     2048
#define LEAK    0.3f

// ---------------------------------------------------------------------------
// Phase 1: P = U @ Win^T + bias, written directly into d_out (T x HID, f32)
// ---------------------------------------------------------------------------
#define GBM 64
#define GBN 64
#define GBK 32

__global__ __launch_bounds__(256) void gemm_p(const float* __restrict__ U,
                                              const float* __restrict__ Win,
                                              const float* __restrict__ bias,
                                              float* __restrict__ P) {
  __shared__ float As[GBM][GBK + 1];
  __shared__ float Bs[GBN][GBK + 1];
  const int bm = blockIdx.x, bn = blockIdx.y;
  const int tid = threadIdx.x;
  const int tx = tid & 15, ty = tid >> 4;

  float acc[4][4];
#pragma unroll
  for (int m = 0; m < 4; ++m)
#pragma unroll
    for (int n = 0; n < 4; ++n) acc[m][n] = 0.f;

  const float* Ub = U + (size_t)bm * GBM * IN_DIM;
  const float* Wb = Win + (size_t)bn * GBN * IN_DIM;

  for (int k0 = 0; k0 < IN_DIM; k0 += GBK) {
#pragma unroll
    for (int v = 0; v < 2; ++v) {
      const int f4 = v * 256 + tid;
      const int row = f4 >> 3;
      const int c4 = (f4 & 7) << 2;
      const float4 a = *(const float4*)(Ub + (size_t)row * IN_DIM + k0 + c4);
      As[row][c4 + 0] = a.x; As[row][c4 + 1] = a.y;
      As[row][c4 + 2] = a.z; As[row][c4 + 3] = a.w;
      const float4 b = *(const float4*)(Wb + (size_t)row * IN_DIM + k0 + c4);
      Bs[row][c4 + 0] = b.x; Bs[row][c4 + 1] = b.y;
      Bs[row][c4 + 2] = b.z; Bs[row][c4 + 3] = b.w;
    }
    __syncthreads();
#pragma unroll 8
    for (int k = 0; k < GBK; ++k) {
      float a[4], b[4];
#pragma unroll
      for (int m = 0; m < 4; ++m) a[m] = As[ty * 4 + m][k];
#pragma unroll
      for (int n = 0; n < 4; ++n) b[n] = Bs[tx * 4 + n][k];
#pragma unroll
      for (int m = 0; m < 4; ++m)
#pragma unroll
        for (int n = 0; n < 4; ++n)
          acc[m][n] = fmaf(a[m], b[n], acc[m][n]);
    }
    __syncthreads();
  }

#pragma unroll
  for (int m = 0; m < 4; ++m) {
    const int gr = bm * GBM + ty * 4 + m;
#pragma unroll
    for (int n = 0; n < 4; ++n) {
      const int gc = bn * GBN + tx * 4 + n;
      P[(size_t)gr * HID + gc] = acc[m][n] + bias[gc];
    }
  }
}

// ---------------------------------------------------------------------------
// Phase 2: persistent recurrence, PER-WAVE SENTINEL exchange.
//   - producer wave (4 rows): 4 relaxed agent f32 value-stores ->
//     s_waitcnt vmcnt(0) (ack) -> one 4B sentinel store (= t+1).
//   - consumer thread tid needs rows tid*4..tid*4+3 = output of EXACTLY one
//     source wave -> polls ONE 4B sentinel (8x less poll traffic than the
//     round-3 tagged words), then loads its 4 values (1 pipelined RTT).
//   - double-buffered LDS staging -> single __syncthreads per step (safe:
//     a buffer is only re-written after the barrier that proves all its
//     readers finished).
//   - W streams from XCD L2 (register pinning failed in round 4: allocator
//     refuses ~200 VGPRs and spills; plain streaming is faster).
// ---------------------------------------------------------------------------
#define NB   64                  // blocks
#define NT   512                 // threads per block
#define NW   (NT / 64)           // 8 waves per block
#define RPB  (HID / NB)          // 32 rows per block
#define TPR  16                  // threads per row
#define NF4  (HID / (TPR * 4))   // 32 float4 chunks per row

__device__ __forceinline__ float fast_tanh(float x) {
  const float e = __expf(2.f * x);
  return 1.f - 2.f / (e + 1.f);
}

__global__ __launch_bounds__(NT, 1) void esn_recur(const float* __restrict__ W,
                                                   float* __restrict__ out,
                                                   unsigned* __restrict__ sent,
                                                   float* __restrict__ hsl) {
  const int tid  = threadIdx.x;
  const int j    = tid & (TPR - 1);      // lane within row
  const int rl   = tid >> 4;             // local row
  const int row  = blockIdx.x * RPB + rl;
  const int lane = tid & 63;
  const int wid  = tid >> 6;
  const int sidx = blockIdx.x * NW + wid;   // my wave's sentinel

  __shared__ float hs[2][HID];           // double-buffered h staging

  const float4* wrow = (const float4*)(W + (size_t)row * HID);

  // ---- t = 0: h0 = leak * tanh(P0) ----
  float hp = LEAK * fast_tanh(out[row]); // all 16 lanes of a row identical
  if (j == 0) {
    out[row] = hp;
    __hip_atomic_store(&hsl[row], hp, __ATOMIC_RELAXED, __HIP_MEMORY_SCOPE_AGENT);
  }
  asm volatile("s_waitcnt vmcnt(0)" ::: "memory");   // values at LLC
  if (lane == 0)
    __hip_atomic_store(&sent[sidx], 1u, __ATOMIC_RELAXED, __HIP_MEMORY_SCOPE_AGENT);

  for (int t = 1; t < T_STEPS; ++t) {
    float* __restrict__ ocur = out + (size_t)t * HID;
    const float p = ocur[row];           // issue early, hide under the spin
    asm volatile("" :: "v"(p));          // forbid sinking past the poll loop

    // ---- poll my source wave's sentinel (one 4B word) ----
    unsigned v;
    do {
      v = __hip_atomic_load(&sent[tid], __ATOMIC_RELAXED, __HIP_MEMORY_SCOPE_AGENT);
    } while (v < (unsigned)t);

    // ---- fetch my 4 h values (pipelined, ~1 RTT) ----
    const float* __restrict__ src = hsl + (size_t)((t - 1) & 1) * HID + tid * 4;
    float4 hv4;
    hv4.x = __hip_atomic_load(&src[0], __ATOMIC_RELAXED, __HIP_MEMORY_SCOPE_AGENT);
    hv4.y = __hip_atomic_load(&src[1], __ATOMIC_RELAXED, __HIP_MEMORY_SCOPE_AGENT);
    hv4.z = __hip_atomic_load(&src[2], __ATOMIC_RELAXED, __HIP_MEMORY_SCOPE_AGENT);
    hv4.w = __hip_atomic_load(&src[3], __ATOMIC_RELAXED, __HIP_MEMORY_SCOPE_AGENT);

    float* __restrict__ hb = hs[(t - 1) & 1];
    *(float4*)&hb[tid * 4] = hv4;
    __syncthreads();                     // h_{t-1} staged (single barrier/step)

    // ---- compute: dot(W[row], h) over 16 lanes ----
    float4 acc = make_float4(0.f, 0.f, 0.f, 0.f);
#pragma unroll
    for (int i = 0; i < NF4; ++i) {
      const float4 wv = wrow[i * TPR + j];            // streams from XCD L2
      const float4 hv = *(const float4*)&hb[(i * TPR + j) * 4];
      acc.x = fmaf(wv.x, hv.x, acc.x);
      acc.y = fmaf(wv.y, hv.y, acc.y);
      acc.z = fmaf(wv.z, hv.z, acc.z);
      acc.w = fmaf(wv.w, hv.w, acc.w);
    }
    float a = (acc.x + acc.y) + (acc.z + acc.w);
    a += __shfl_xor(a, 1, TPR);
    a += __shfl_xor(a, 2, TPR);
    a += __shfl_xor(a, 4, TPR);
    a += __shfl_xor(a, 8, TPR);          // all 16 lanes hold the full dot

    const float h = (1.f - LEAK) * hp + LEAK * fast_tanh(p + a);
    hp = h;

    // ---- publish: 4 value stores per wave -> ack -> 1 sentinel ----
    if (j == 0) {
      ocur[row] = h;                     // plain cached store (own rows only)
      __hip_atomic_store(&hsl[(size_t)(t & 1) * HID + row], h,
                         __ATOMIC_RELAXED, __HIP_MEMORY_SCOPE_AGENT);
    }
    asm volatile("s_waitcnt vmcnt(0)" ::: "memory");
    if (lane == 0)
      __hip_atomic_store(&sent[sidx], (unsigned)(t + 1),
                         __ATOMIC_RELAXED, __HIP_MEMORY_SCOPE_AGENT);
  }
}

// ---------------------------------------------------------------------------
extern "C" void kernel_launch(void* const* d_in, const int* in_sizes, int n_in,
                              void* d_out, int out_size, void* d_ws, size_t ws_size,
                              hipStream_t stream) {
  const float* U    = (const float*)d_in[0];
  const float* Win  = (const float*)d_in[1];
  const float* W    = (const float*)d_in[2];
  const float* bias = (const float*)d_in[3];
  float* out = (float*)d_out;
  unsigned* sent = (unsigned*)d_ws;                      // 512 * 4B
  float* hsl = (float*)((char*)d_ws + 4096);             // 2 * 2048 * 4B ring

  // sentinels must start at 0 every launch (tags are t+1 >= 1)
  hipMemsetAsync(d_ws, 0, 4096 + 2 * HID * sizeof(float), stream);

  dim3 ggrid(T_STEPS / GBM, HID / GBN);
  gemm_p<<<ggrid, 256, 0, stream>>>(U, Win, bias, out);

  esn_recur<<<NB, NT, 0, stream>>>(W, out, sent, hsl);
}

// Round 6
// 15042.694 us; speedup vs baseline: 1.3763x; 1.3763x over previous
//
#include <hip/hip_runtime.h>
#include <hip/hip_bf16.h>
#include <math.h>

#define T_STEPS 4096
#define IN_DIM  512
#define HID     2048
#define LEAK    0.3f

// ---------------------------------------------------------------------------
// Phase 1: P = U @ Win^T + bias, written directly into d_out (T x HID, f32)
// ---------------------------------------------------------------------------
#define GBM 64
#define GBN 64
#define GBK 32

__global__ __launch_bounds__(256) void gemm_p(const float* __restrict__ U,
                                              const float* __restrict__ Win,
                                              const float* __restrict__ bias,
                                              float* __restrict__ P) {
  __shared__ float As[GBM][GBK + 1];
  __shared__ float Bs[GBN][GBK + 1];
  const int bm = blockIdx.x, bn = blockIdx.y;
  const int tid = threadIdx.x;
  const int tx = tid & 15, ty = tid >> 4;

  float acc[4][4];
#pragma unroll
  for (int m = 0; m < 4; ++m)
#pragma unroll
    for (int n = 0; n < 4; ++n) acc[m][n] = 0.f;

  const float* Ub = U + (size_t)bm * GBM * IN_DIM;
  const float* Wb = Win + (size_t)bn * GBN * IN_DIM;

  for (int k0 = 0; k0 < IN_DIM; k0 += GBK) {
#pragma unroll
    for (int v = 0; v < 2; ++v) {
      const int f4 = v * 256 + tid;
      const int row = f4 >> 3;
      const int c4 = (f4 & 7) << 2;
      const float4 a = *(const float4*)(Ub + (size_t)row * IN_DIM + k0 + c4);
      As[row][c4 + 0] = a.x; As[row][c4 + 1] = a.y;
      As[row][c4 + 2] = a.z; As[row][c4 + 3] = a.w;
      const float4 b = *(const float4*)(Wb + (size_t)row * IN_DIM + k0 + c4);
      Bs[row][c4 + 0] = b.x; Bs[row][c4 + 1] = b.y;
      Bs[row][c4 + 2] = b.z; Bs[row][c4 + 3] = b.w;
    }
    __syncthreads();
#pragma unroll 8
    for (int k = 0; k < GBK; ++k) {
      float a[4], b[4];
#pragma unroll
      for (int m = 0; m < 4; ++m) a[m] = As[ty * 4 + m][k];
#pragma unroll
      for (int n = 0; n < 4; ++n) b[n] = Bs[tx * 4 + n][k];
#pragma unroll
      for (int m = 0; m < 4; ++m)
#pragma unroll
        for (int n = 0; n < 4; ++n)
          acc[m][n] = fmaf(a[m], b[n], acc[m][n]);
    }
    __syncthreads();
  }

#pragma unroll
  for (int m = 0; m < 4; ++m) {
    const int gr = bm * GBM + ty * 4 + m;
#pragma unroll
    for (int n = 0; n < 4; ++n) {
      const int gc = bn * GBN + tx * 4 + n;
      P[(size_t)gr * HID + gc] = acc[m][n] + bias[gc];
    }
  }
}

// ---------------------------------------------------------------------------
// Phase 2: persistent recurrence, single-hop tagged-word exchange
// (round-3 structure; the ONLY protocol change vs round 3 is the
//  CONCURRENT 4-word poll).
//   - h published as 64-bit {tag = t+1, f32 bits} via relaxed AGENT-scope
//     atomic store (bypasses non-coherent XCD L2, visible at LLC). Detect
//     IS data arrival -- zero extra hops (rounds 2/5 proved hops dominate).
//   - concurrent poll: 4 loads issued back-to-back each round -> 1 LLC RTT
//     per round instead of 4 serial RTTs; monotonic ready-transition makes
//     the final round's values valid.
//   - early P load WITHOUT a forced wait: its s_waitcnt lands at first use
//     after the barrier, overlapped with the spin.
//   - W streams from XCD L2 (register pinning refused by allocator, round 4).
// ---------------------------------------------------------------------------
#define NB   64                  // blocks
#define NT   512                 // threads per block
#define RPB  (HID / NB)          // 32 rows per block
#define TPR  16                  // threads per row
#define NF4  (HID / (TPR * 4))   // 32 float4 chunks per row

__device__ __forceinline__ float fast_tanh(float x) {
  const float e = __expf(2.f * x);
  return 1.f - 2.f / (e + 1.f);
}

__device__ __forceinline__ void pub(unsigned long long* p, unsigned tag, float v) {
  const unsigned long long w =
      ((unsigned long long)tag << 32) | (unsigned long long)__float_as_uint(v);
  __hip_atomic_store(p, w, __ATOMIC_RELAXED, __HIP_MEMORY_SCOPE_AGENT);
}

__global__ __launch_bounds__(NT, 1) void esn_recur(const float* __restrict__ W,
                                                   float* __restrict__ out,
                                                   unsigned long long* __restrict__ slots) {
  const int tid = threadIdx.x;
  const int j   = tid & (TPR - 1);       // lane within row
  const int rl  = tid >> 4;              // local row
  const int row = blockIdx.x * RPB + rl;

  __shared__ float hs[HID];              // 8 KB staging for h_{t-1}

  const float4* wrow = (const float4*)(W + (size_t)row * HID);

  // ---- t = 0: h0 = leak * tanh(P0), publish with tag 1 into slot 0 ----
  float hp = LEAK * fast_tanh(out[row]); // all 16 lanes compute identically
  if (j == 0) {
    pub(&slots[row], 1u, hp);
    out[row] = hp;
  }

  for (int t = 1; t < T_STEPS; ++t) {
    float* __restrict__ ocur = out + (size_t)t * HID;
    const float p = ocur[row];           // issued early; wait deferred to use

    // ---- fetch: poll 4 tagged words CONCURRENTLY (1 RTT per round) ----
    const unsigned long long* __restrict__ s4 =
        slots + (size_t)((t - 1) & 1) * HID + (size_t)tid * 4;
    const unsigned long long we = (unsigned long long)(unsigned)t << 32;
    unsigned long long w0, w1, w2, w3;
    do {
      w0 = __hip_atomic_load(&s4[0], __ATOMIC_RELAXED, __HIP_MEMORY_SCOPE_AGENT);
      w1 = __hip_atomic_load(&s4[1], __ATOMIC_RELAXED, __HIP_MEMORY_SCOPE_AGENT);
      w2 = __hip_atomic_load(&s4[2], __ATOMIC_RELAXED, __HIP_MEMORY_SCOPE_AGENT);
      w3 = __hip_atomic_load(&s4[3], __ATOMIC_RELAXED, __HIP_MEMORY_SCOPE_AGENT);
    } while ((((w0 ^ we) | (w1 ^ we) | (w2 ^ we) | (w3 ^ we)) >> 32) != 0ull);

    float4 hv4;
    hv4.x = __uint_as_float((unsigned)w0);
    hv4.y = __uint_as_float((unsigned)w1);
    hv4.z = __uint_as_float((unsigned)w2);
    hv4.w = __uint_as_float((unsigned)w3);

    __syncthreads();                     // prior step's LDS reads are done
    *(float4*)&hs[tid * 4] = hv4;
    __syncthreads();                     // h_{t-1} staged

    // ---- compute: dot(W[row], h) over 16 lanes ----
    float4 acc = make_float4(0.f, 0.f, 0.f, 0.f);
#pragma unroll
    for (int i = 0; i < NF4; ++i) {
      const float4 wv = wrow[i * TPR + j];            // streams from XCD L2
      const float4 hv = *(const float4*)&hs[(i * TPR + j) * 4];
      acc.x = fmaf(wv.x, hv.x, acc.x);
      acc.y = fmaf(wv.y, hv.y, acc.y);
      acc.z = fmaf(wv.z, hv.z, acc.z);
      acc.w = fmaf(wv.w, hv.w, acc.w);
    }
    float a = (acc.x + acc.y) + (acc.z + acc.w);
    a += __shfl_xor(a, 1, TPR);
    a += __shfl_xor(a, 2, TPR);
    a += __shfl_xor(a, 4, TPR);
    a += __shfl_xor(a, 8, TPR);          // all lanes hold the full dot

    const float h = (1.f - LEAK) * hp + LEAK * fast_tanh(p + a);
    hp = h;
    if (j == 0) {
      pub(&slots[(size_t)(t & 1) * HID + row], (unsigned)(t + 1), h);
      ocur[row] = h;                     // plain cached store (own XCD only)
    }
  }
}

// ---------------------------------------------------------------------------
extern "C" void kernel_launch(void* const* d_in, const int* in_sizes, int n_in,
                              void* d_out, int out_size, void* d_ws, size_t ws_size,
                              hipStream_t stream) {
  const float* U    = (const float*)d_in[0];
  const float* Win  = (const float*)d_in[1];
  const float* W    = (const float*)d_in[2];
  const float* bias = (const float*)d_in[3];
  float* out = (float*)d_out;
  unsigned long long* slots = (unsigned long long*)d_ws;

  // wipe tags (also clears stale tags between graph replays); tag 0 is
  // never a valid tag (tags are t+1 >= 1), so memset can't false-match
  hipMemsetAsync(d_ws, 0, 2 * HID * sizeof(unsigned long long), stream);

  dim3 ggrid(T_STEPS / GBM, HID / GBN);
  gemm_p<<<ggrid, 256, 0, stream>>>(U, Win, bias, out);

  esn_recur<<<NB, NT, 0, stream>>>(W, out, slots);
}

// Round 7
// 12060.253 us; speedup vs baseline: 1.7166x; 1.2473x over previous
//
#include <hip/hip_runtime.h>
#include <hip/hip_bf16.h>
#include <math.h>

#define T_STEPS 4096
#define IN_DIM  512
#define HID     2048
#define LEAK    0.3f

// ---------------------------------------------------------------------------
// Phase 1: P = U @ Win^T + bias, written directly into d_out (T x HID, f32)
// ---------------------------------------------------------------------------
#define GBM 64
#define GBN 64
#define GBK 32

__global__ __launch_bounds__(256) void gemm_p(const float* __restrict__ U,
                                              const float* __restrict__ Win,
                                              const float* __restrict__ bias,
                                              float* __restrict__ P) {
  __shared__ float As[GBM][GBK + 1];
  __shared__ float Bs[GBN][GBK + 1];
  const int bm = blockIdx.x, bn = blockIdx.y;
  const int tid = threadIdx.x;
  const int tx = tid & 15, ty = tid >> 4;

  float acc[4][4];
#pragma unroll
  for (int m = 0; m < 4; ++m)
#pragma unroll
    for (int n = 0; n < 4; ++n) acc[m][n] = 0.f;

  const float* Ub = U + (size_t)bm * GBM * IN_DIM;
  const float* Wb = Win + (size_t)bn * GBN * IN_DIM;

  for (int k0 = 0; k0 < IN_DIM; k0 += GBK) {
#pragma unroll
    for (int v = 0; v < 2; ++v) {
      const int f4 = v * 256 + tid;
      const int row = f4 >> 3;
      const int c4 = (f4 & 7) << 2;
      const float4 a = *(const float4*)(Ub + (size_t)row * IN_DIM + k0 + c4);
      As[row][c4 + 0] = a.x; As[row][c4 + 1] = a.y;
      As[row][c4 + 2] = a.z; As[row][c4 + 3] = a.w;
      const float4 b = *(const float4*)(Wb + (size_t)row * IN_DIM + k0 + c4);
      Bs[row][c4 + 0] = b.x; Bs[row][c4 + 1] = b.y;
      Bs[row][c4 + 2] = b.z; Bs[row][c4 + 3] = b.w;
    }
    __syncthreads();
#pragma unroll 8
    for (int k = 0; k < GBK; ++k) {
      float a[4], b[4];
#pragma unroll
      for (int m = 0; m < 4; ++m) a[m] = As[ty * 4 + m][k];
#pragma unroll
      for (int n = 0; n < 4; ++n) b[n] = Bs[tx * 4 + n][k];
#pragma unroll
      for (int m = 0; m < 4; ++m)
#pragma unroll
        for (int n = 0; n < 4; ++n)
          acc[m][n] = fmaf(a[m], b[n], acc[m][n]);
    }
    __syncthreads();
  }

#pragma unroll
  for (int m = 0; m < 4; ++m) {
    const int gr = bm * GBM + ty * 4 + m;
#pragma unroll
    for (int n = 0; n < 4; ++n) {
      const int gc = bn * GBN + tx * 4 + n;
      P[(size_t)gr * HID + gc] = acc[m][n] + bias[gc];
    }
  }
}

// ---------------------------------------------------------------------------
// Phase 2: persistent recurrence, W RESIDENT IN LDS.
//   Round-6 insight: per-CU L2 BW is only ~135 GB/s; streaming the 256 KB
//   W slice from L2 every step was ~1.9 us/step -- the dominant cost, not
//   the exchange protocol. Fix: 128 blocks x 16 rows -> 128 KB W slice,
//   loaded into LDS once in the prologue (LDS = 614 GB/s/CU, no fabric).
//   Exchange protocol = round 3's winner (serial spin, tag+value words):
//   - h published as 64-bit {tag = t+1, f32 bits}, relaxed AGENT-scope
//     atomic store (bypasses non-coherent XCD L2, visible at LLC); detect
//     IS data arrival, zero extra hops.
//   - NT=256 -> 8 words/thread: SPIN ON WORD 0 ONLY (1 outstanding poll
//     load/thread -- round 6 proved wide polling slows the producer),
//     then batch-verify words 1..7 (same producer block, ~1 extra RTT).
//   - double-buffered LDS h staging, ONE __syncthreads per step (ring-2
//     induction: a buffer is rewritten only after the barrier that proves
//     all its readers finished).
// ---------------------------------------------------------------------------
#define NB   128                 // blocks
#define NT   256                 // threads per block
#define RPB  (HID / NB)          // 16 rows per block
#define TPR  16                  // threads per row
#define NF4  (HID / (TPR * 4))   // 32 float4 chunks per thread-dot
#define WPT  (HID / NT)          // 8 polled words per thread

__device__ __forceinline__ float fast_tanh(float x) {
  const float e = __expf(2.f * x);
  return 1.f - 2.f / (e + 1.f);
}

__device__ __forceinline__ void pub(unsigned long long* p, unsigned tag, float v) {
  const unsigned long long w =
      ((unsigned long long)tag << 32) | (unsigned long long)__float_as_uint(v);
  __hip_atomic_store(p, w, __ATOMIC_RELAXED, __HIP_MEMORY_SCOPE_AGENT);
}

__global__ __launch_bounds__(NT, 1) void esn_recur(const float* __restrict__ W,
                                                   float* __restrict__ out,
                                                   unsigned long long* __restrict__ slots) {
  const int tid = threadIdx.x;
  const int j   = tid & (TPR - 1);       // lane within row
  const int rl  = tid >> 4;              // local row (0..15)
  const int row = blockIdx.x * RPB + rl;

  __shared__ float Wl[RPB][HID];         // 128 KB: this block's W rows
  __shared__ float hs[2][HID];           // 16 KB: double-buffered h staging

  // ---- prologue: stage W slice into LDS (one-time) ----
  {
    const float4* wsrc = (const float4*)(W + (size_t)blockIdx.x * RPB * HID);
    float4* wdst = (float4*)&Wl[0][0];
#pragma unroll 4
    for (int f = tid; f < RPB * HID / 4; f += NT) wdst[f] = wsrc[f];
  }

  // ---- t = 0: h0 = leak * tanh(P0), publish with tag 1 into slot 0 ----
  float hp = LEAK * fast_tanh(out[row]); // all 16 lanes of a row identical
  if (j == 0) {
    pub(&slots[row], 1u, hp);
    out[row] = hp;
  }

  for (int t = 1; t < T_STEPS; ++t) {
    float* __restrict__ ocur = out + (size_t)t * HID;
    const float p = ocur[row];           // issued early; wait lands at use

    // ---- fetch: spin on word 0 only, then batch-verify words 1..7 ----
    const unsigned long long* __restrict__ s8 =
        slots + (size_t)((t - 1) & 1) * HID + (size_t)tid * WPT;
    const unsigned tg = (unsigned)t;     // tag of h_{t-1}
    unsigned long long w[WPT];
    do {
      w[0] = __hip_atomic_load(&s8[0], __ATOMIC_RELAXED, __HIP_MEMORY_SCOPE_AGENT);
    } while ((unsigned)(w[0] >> 32) != tg);
    bool ok;
    do {
      ok = true;
#pragma unroll
      for (int q = 1; q < WPT; ++q)
        w[q] = __hip_atomic_load(&s8[q], __ATOMIC_RELAXED, __HIP_MEMORY_SCOPE_AGENT);
#pragma unroll
      for (int q = 1; q < WPT; ++q)
        ok = ok && ((unsigned)(w[q] >> 32) == tg);
    } while (!ok);

    float* __restrict__ hb = hs[(t - 1) & 1];
    float4 v0, v1;
    v0.x = __uint_as_float((unsigned)w[0]);
    v0.y = __uint_as_float((unsigned)w[1]);
    v0.z = __uint_as_float((unsigned)w[2]);
    v0.w = __uint_as_float((unsigned)w[3]);
    v1.x = __uint_as_float((unsigned)w[4]);
    v1.y = __uint_as_float((unsigned)w[5]);
    v1.z = __uint_as_float((unsigned)w[6]);
    v1.w = __uint_as_float((unsigned)w[7]);
    *(float4*)&hb[tid * WPT]     = v0;
    *(float4*)&hb[tid * WPT + 4] = v1;
    __syncthreads();                     // h_{t-1} staged (single barrier)

    // ---- compute: dot(W[row], h), both operands from LDS ----
    const float* __restrict__ wl = &Wl[rl][0];
    float4 acc = make_float4(0.f, 0.f, 0.f, 0.f);
#pragma unroll
    for (int i = 0; i < NF4; ++i) {
      const int idx = (i * TPR + j) * 4;
      const float4 wv = *(const float4*)&wl[idx];
      const float4 hv = *(const float4*)&hb[idx];
      acc.x = fmaf(wv.x, hv.x, acc.x);
      acc.y = fmaf(wv.y, hv.y, acc.y);
      acc.z = fmaf(wv.z, hv.z, acc.z);
      acc.w = fmaf(wv.w, hv.w, acc.w);
    }
    float a = (acc.x + acc.y) + (acc.z + acc.w);
    a += __shfl_xor(a, 1, TPR);
    a += __shfl_xor(a, 2, TPR);
    a += __shfl_xor(a, 4, TPR);
    a += __shfl_xor(a, 8, TPR);          // all 16 lanes hold the full dot

    const float h = (1.f - LEAK) * hp + LEAK * fast_tanh(p + a);
    hp = h;
    if (j == 0) {
      pub(&slots[(size_t)(t & 1) * HID + row], (unsigned)(t + 1), h);
      ocur[row] = h;                     // plain cached store (own column)
    }
  }
}

// ---------------------------------------------------------------------------
extern "C" void kernel_launch(void* const* d_in, const int* in_sizes, int n_in,
                              void* d_out, int out_size, void* d_ws, size_t ws_size,
                              hipStream_t stream) {
  const float* U    = (const float*)d_in[0];
  const float* Win  = (const float*)d_in[1];
  const float* W    = (const float*)d_in[2];
  const float* bias = (const float*)d_in[3];
  float* out = (float*)d_out;
  unsigned long long* slots = (unsigned long long*)d_ws;

  // wipe tags (also clears stale tags between graph replays); tag 0 is
  // never a valid tag (tags are t+1 >= 1), so memset can't false-match
  hipMemsetAsync(d_ws, 0, 2 * HID * sizeof(unsigned long long), stream);

  dim3 ggrid(T_STEPS / GBM, HID / GBN);
  gemm_p<<<ggrid, 256, 0, stream>>>(U, Win, bias, out);

  esn_recur<<<NB, NT, 0, stream>>>(W, out, slots);
}

// Round 8
// 11839.070 us; speedup vs baseline: 1.7487x; 1.0187x over previous
//
#include <hip/hip_runtime.h>
#include <hip/hip_bf16.h>
#include <math.h>

#define T_STEPS 4096
#define IN_DIM  512
#define HID     2048
#define LEAK    0.3f

// ---------------------------------------------------------------------------
// Phase 1: P = U @ Win^T + bias, written directly into d_out (T x HID, f32)
// ---------------------------------------------------------------------------
#define GBM 64
#define GBN 64
#define GBK 32

__global__ __launch_bounds__(256) void gemm_p(const float* __restrict__ U,
                                              const float* __restrict__ Win,
                                              const float* __restrict__ bias,
                                              float* __restrict__ P) {
  __shared__ float As[GBM][GBK + 1];
  __shared__ float Bs[GBN][GBK + 1];
  const int bm = blockIdx.x, bn = blockIdx.y;
  const int tid = threadIdx.x;
  const int tx = tid & 15, ty = tid >> 4;

  float acc[4][4];
#pragma unroll
  for (int m = 0; m < 4; ++m)
#pragma unroll
    for (int n = 0; n < 4; ++n) acc[m][n] = 0.f;

  const float* Ub = U + (size_t)bm * GBM * IN_DIM;
  const float* Wb = Win + (size_t)bn * GBN * IN_DIM;

  for (int k0 = 0; k0 < IN_DIM; k0 += GBK) {
#pragma unroll
    for (int v = 0; v < 2; ++v) {
      const int f4 = v * 256 + tid;
      const int row = f4 >> 3;
      const int c4 = (f4 & 7) << 2;
      const float4 a = *(const float4*)(Ub + (size_t)row * IN_DIM + k0 + c4);
      As[row][c4 + 0] = a.x; As[row][c4 + 1] = a.y;
      As[row][c4 + 2] = a.z; As[row][c4 + 3] = a.w;
      const float4 b = *(const float4*)(Wb + (size_t)row * IN_DIM + k0 + c4);
      Bs[row][c4 + 0] = b.x; Bs[row][c4 + 1] = b.y;
      Bs[row][c4 + 2] = b.z; Bs[row][c4 + 3] = b.w;
    }
    __syncthreads();
#pragma unroll 8
    for (int k = 0; k < GBK; ++k) {
      float a[4], b[4];
#pragma unroll
      for (int m = 0; m < 4; ++m) a[m] = As[ty * 4 + m][k];
#pragma unroll
      for (int n = 0; n < 4; ++n) b[n] = Bs[tx * 4 + n][k];
#pragma unroll
      for (int m = 0; m < 4; ++m)
#pragma unroll
        for (int n = 0; n < 4; ++n)
          acc[m][n] = fmaf(a[m], b[n], acc[m][n]);
    }
    __syncthreads();
  }

#pragma unroll
  for (int m = 0; m < 4; ++m) {
    const int gr = bm * GBM + ty * 4 + m;
#pragma unroll
    for (int n = 0; n < 4; ++n) {
      const int gc = bn * GBN + tx * 4 + n;
      P[(size_t)gr * HID + gc] = acc[m][n] + bias[gc];
    }
  }
}

// ---------------------------------------------------------------------------
// Phase 2: persistent recurrence, W RESIDENT IN REGISTERS.
//   Round-7 insight: the compute phase was LDS-pipe-bound (256 KB/step/CU
//   at 128 B/cy ~ 2048 cy serial after h arrives). Fix: W fragment (32
//   float4 = 128 VGPR/thread) lives in registers for the whole kernel.
//   This works NOW because NT=256 -> 4 waves/block -> 1 wave/SIMD -> 512
//   VGPR budget (R3/R4 ran NT=512 -> 256 budget -> allocator rematerialized
//   /spilled). LDS holds only the 16 KB h double-buffer; compute LDS
//   traffic halves to 128 KB/step (h re-read by 16 rows).
//   Exchange protocol = round 7 (round-3 winner + spin-on-one):
//   - h published as 64-bit {tag = t+1, f32 bits}, relaxed AGENT-scope
//     atomic store (bypasses non-coherent XCD L2); detect IS data arrival.
//   - spin on word 0 only (1 outstanding poll load/thread; round 6 proved
//     wide polling slows the producer), then batch-verify words 1..7.
//   - double-buffered LDS h staging, ONE __syncthreads per step (ring-2
//     induction: a buffer is rewritten only after the barrier that proves
//     all its readers finished).
// ---------------------------------------------------------------------------
#define NB   128                 // blocks
#define NT   256                 // threads per block
#define RPB  (HID / NB)          // 16 rows per block
#define TPR  16                  // threads per row
#define NF4  (HID / (TPR * 4))   // 32 float4 chunks per thread-dot
#define WPT  (HID / NT)          // 8 polled words per thread

__device__ __forceinline__ float fast_tanh(float x) {
  const float e = __expf(2.f * x);
  return 1.f - 2.f / (e + 1.f);
}

__device__ __forceinline__ void pub(unsigned long long* p, unsigned tag, float v) {
  const unsigned long long w =
      ((unsigned long long)tag << 32) | (unsigned long long)__float_as_uint(v);
  __hip_atomic_store(p, w, __ATOMIC_RELAXED, __HIP_MEMORY_SCOPE_AGENT);
}

__global__ __launch_bounds__(NT, 1) void esn_recur(const float* __restrict__ W,
                                                   float* __restrict__ out,
                                                   unsigned long long* __restrict__ slots) {
  const int tid = threadIdx.x;
  const int j   = tid & (TPR - 1);       // lane within row
  const int rl  = tid >> 4;              // local row (0..15)
  const int row = blockIdx.x * RPB + rl;

  __shared__ float hs[2][HID];           // 16 KB: double-buffered h staging

  // ---- W fragment into registers (one-time; stays live across t-loop).
  // 32 float4 = 128 VGPR. Budget is 512 (1 wave/SIMD), so no spill.
  float4 wr[NF4];
  {
    const float4* wrow = (const float4*)(W + (size_t)row * HID);
#pragma unroll
    for (int i = 0; i < NF4; ++i) wr[i] = wrow[i * TPR + j];
  }

  // ---- t = 0: h0 = leak * tanh(P0), publish with tag 1 into slot 0 ----
  float hp = LEAK * fast_tanh(out[row]); // all 16 lanes of a row identical
  if (j == 0) {
    pub(&slots[row], 1u, hp);
    out[row] = hp;
  }

  for (int t = 1; t < T_STEPS; ++t) {
    float* __restrict__ ocur = out + (size_t)t * HID;
    const float p = ocur[row];           // issued early; wait lands at use

    // ---- fetch: spin on word 0 only, then batch-verify words 1..7 ----
    const unsigned long long* __restrict__ s8 =
        slots + (size_t)((t - 1) & 1) * HID + (size_t)tid * WPT;
    const unsigned tg = (unsigned)t;     // tag of h_{t-1}
    unsigned long long w[WPT];
    do {
      w[0] = __hip_atomic_load(&s8[0], __ATOMIC_RELAXED, __HIP_MEMORY_SCOPE_AGENT);
    } while ((unsigned)(w[0] >> 32) != tg);
    bool ok;
    do {
      ok = true;
#pragma unroll
      for (int q = 1; q < WPT; ++q)
        w[q] = __hip_atomic_load(&s8[q], __ATOMIC_RELAXED, __HIP_MEMORY_SCOPE_AGENT);
#pragma unroll
      for (int q = 1; q < WPT; ++q)
        ok = ok && ((unsigned)(w[q] >> 32) == tg);
    } while (!ok);

    float* __restrict__ hb = hs[(t - 1) & 1];
    float4 v0, v1;
    v0.x = __uint_as_float((unsigned)w[0]);
    v0.y = __uint_as_float((unsigned)w[1]);
    v0.z = __uint_as_float((unsigned)w[2]);
    v0.w = __uint_as_float((unsigned)w[3]);
    v1.x = __uint_as_float((unsigned)w[4]);
    v1.y = __uint_as_float((unsigned)w[5]);
    v1.z = __uint_as_float((unsigned)w[6]);
    v1.w = __uint_as_float((unsigned)w[7]);
    *(float4*)&hb[tid * WPT]     = v0;
    *(float4*)&hb[tid * WPT + 4] = v1;
    __syncthreads();                     // h_{t-1} staged (single barrier)

    // ---- compute: dot(W[row], h); W from VGPRs, h from LDS ----
    float4 acc = make_float4(0.f, 0.f, 0.f, 0.f);
#pragma unroll
    for (int i = 0; i < NF4; ++i) {
      const float4 hv = *(const float4*)&hb[(i * TPR + j) * 4];
      acc.x = fmaf(wr[i].x, hv.x, acc.x);
      acc.y = fmaf(wr[i].y, hv.y, acc.y);
      acc.z = fmaf(wr[i].z, hv.z, acc.z);
      acc.w = fmaf(wr[i].w, hv.w, acc.w);
    }
    float a = (acc.x + acc.y) + (acc.z + acc.w);
    a += __shfl_xor(a, 1, TPR);
    a += __shfl_xor(a, 2, TPR);
    a += __shfl_xor(a, 4, TPR);
    a += __shfl_xor(a, 8, TPR);          // all 16 lanes hold the full dot

    const float h = (1.f - LEAK) * hp + LEAK * fast_tanh(p + a);
    hp = h;
    if (j == 0) {
      pub(&slots[(size_t)(t & 1) * HID + row], (unsigned)(t + 1), h);
      ocur[row] = h;                     // plain cached store (own column)
    }
  }
}

// ---------------------------------------------------------------------------
extern "C" void kernel_launch(void* const* d_in, const int* in_sizes, int n_in,
                              void* d_out, int out_size, void* d_ws, size_t ws_size,
                              hipStream_t stream) {
  const float* U    = (const float*)d_in[0];
  const float* Win  = (const float*)d_in[1];
  const float* W    = (const float*)d_in[2];
  const float* bias = (const float*)d_in[3];
  float* out = (float*)d_out;
  unsigned long long* slots = (unsigned long long*)d_ws;

  // wipe tags (also clears stale tags between graph replays); tag 0 is
  // never a valid tag (tags are t+1 >= 1), so memset can't false-match
  hipMemsetAsync(d_ws, 0, 2 * HID * sizeof(unsigned long long), stream);

  dim3 ggrid(T_STEPS / GBM, HID / GBN);
  gemm_p<<<ggrid, 256, 0, stream>>>(U, Win, bias, out);

  esn_recur<<<NB, NT, 0, stream>>>(W, out, slots);
}